// Round 10
// baseline (302.998 us; speedup 1.0000x reference)
//
#include <hip/hip_runtime.h>
#include <math.h>

#define NK        10000
#define LSEQ      512
#define KSMAX     11
#define GRID      1024               // 4 blocks/CU exactly -> co-resident (spin barriers safe)
#define NKEYS     512                // key = (((dl-1)*3+ksi)<<1)|pd ; dl<=85 -> key<=509
#define TOT_SLOT  10512              // NK + <=510 pad slots (one per odd-count key)

// workspace int offsets
#define WS_ARR1   0
#define WS_ARR2   64
#define WS_CNT    128
#define WS_OFF    640
#define WS_ORD    1152
#define WS_ZERO_BYTES (WS_ORD * 4)   // arrive1/2 + cnt + off zeroed by memset

// LDS dword offsets
#define ROWS_DW   (514 * 4)          // f16x8 rows pos=-1..512
#define RED_OFF   ROWS_DW            // 256*10 epilogue scratch
#define SBASE_OFF (ROWS_DW + 2560)   // 512 key bases
#define STOT_OFF  (SBASE_OFF + NKEYS)
#define SM_DW     (STOT_OFF + 1)     // 5129 dw = 20516 B -> 4 blocks/CU = 82 KB

typedef _Float16 half2v __attribute__((ext_vector_type(2)));
union H2U { half2v h; unsigned int u; };

// ---- pair main loop: ONE ds_read_b128 per tap serves 2 kernels (validated in R8) ----
template <int KS>
__device__ __forceinline__ void run_pair(const float4* __restrict__ rows,
                                         const half2v (&wh)[2][KSMAX], const half2v (&bb)[2],
                                         const int (&pq)[2], const int (&lkq)[2],
                                         int dl, int r_lo, int r_hi, int lane,
                                         half2v (&m)[2][4], half2v (&c)[2][4]) {
    const half2v one2  = {(_Float16)1.0f, (_Float16)1.0f};
    const half2v zero2 = {(_Float16)0.0f, (_Float16)0.0f};
    const half2v big2  = {(_Float16)16384.0f, (_Float16)16384.0f};
    const half2v ninf2 = {(_Float16)(-INFINITY), (_Float16)(-INFINITY)};
    for (int r0 = r_lo; r0 < r_hi; r0 += 64) {
        const int r = r0 + lane;
        half2v a[2][4];
        #pragma unroll
        for (int q = 0; q < 2; ++q) {
            #pragma unroll
            for (int i = 0; i < 4; ++i) a[q][i] = bb[q];
        }
        int pos = r;
        #pragma unroll
        for (int j = 0; j < KS; ++j) {
            int pc = min(max(pos, -1), LSEQ);          // v_med3_i32; rows -1/512 are zeros
            float4 rr = rows[pc + 1];
            half2v v0 = ((half2v*)&rr)[0];
            half2v v1 = ((half2v*)&rr)[1];
            half2v v2 = ((half2v*)&rr)[2];
            half2v v3 = ((half2v*)&rr)[3];
            #pragma unroll
            for (int q = 0; q < 2; ++q) {
                half2v wj = wh[q][j];
                a[q][0] += wj * v0;
                a[q][1] += wj * v1;
                a[q][2] += wj * v2;
                a[q][3] += wj * v3;
            }
            pos += dl;
        }
        #pragma unroll
        for (int q = 0; q < 2; ++q) {
            unsigned t = (unsigned)(r + pq[q]);
            bool valid = t < (unsigned)lkq[q];
            #pragma unroll
            for (int i = 0; i < 4; ++i) {
                half2v av = valid ? a[q][i] : ninf2;   // -inf: neutral for max, step()->0
                m[q][i] = __builtin_elementwise_max(m[q][i], av);
                c[q][i] += __builtin_elementwise_min(
                               __builtin_elementwise_max(av * big2, zero2), one2);
            }
        }
    }
}

__global__ __launch_bounds__(256, 4) void rocket_kernel(
    const float* __restrict__ x, const float* __restrict__ W,
    const float* __restrict__ bias, const int* __restrict__ dil,
    const int* __restrict__ lo, int* __restrict__ wsI,
    float* __restrict__ out) {
    __shared__ __align__(16) float sm[SM_DW];
    int* smi = (int*)sm;
    const int tid  = threadIdx.x;
    const int wave = tid >> 6;
    const int lane = tid & 63;
    const int g    = blockIdx.x * 256 + tid;     // global thread id, covers > NK

    // ---- phase 0: distributed classify + count; init ord ----
    int mykey = -1;
    if (g < NK) {
        const float* wr = W + (size_t)g * KSMAX;
        float w7 = wr[7], w8 = wr[8], w9 = wr[9], w10 = wr[10];
        int ksi = (w7 == 0.f && w8 == 0.f && w9 == 0.f && w10 == 0.f) ? 0
                : ((w9 == 0.f && w10 == 0.f) ? 1 : 2);
        int d = dil[g];
        int pd = (lo[g] - LSEQ + d * (6 + 2 * ksi)) > 0;
        mykey = (((d - 1) * 3 + ksi) << 1) | pd;
        atomicAdd(&wsI[WS_CNT + mykey], 1);
    }
    if (g < TOT_SLOT) wsI[WS_ORD + g] = -1;

    // ---- stage x -> LDS as f16 rows (overlaps barrier-1 latency) ----
    #pragma unroll
    for (int i = 0; i < 2; ++i) {
        int p = tid + i * 256;
        half2v h0 = {(_Float16)x[0 * LSEQ + p], (_Float16)x[1 * LSEQ + p]};
        half2v h1 = {(_Float16)x[2 * LSEQ + p], (_Float16)x[3 * LSEQ + p]};
        half2v h2 = {(_Float16)x[4 * LSEQ + p], (_Float16)x[5 * LSEQ + p]};
        half2v h3 = {(_Float16)x[6 * LSEQ + p], (_Float16)x[7 * LSEQ + p]};
        float4 v;
        ((half2v*)&v)[0] = h0;
        ((half2v*)&v)[1] = h1;
        ((half2v*)&v)[2] = h2;
        ((half2v*)&v)[3] = h3;
        *(float4*)(sm + (size_t)(p + 1) * 4) = v;
    }
    if (tid < 4)           sm[tid] = 0.0f;                   // row pos=-1
    else if (tid < 8)      sm[513 * 4 + (tid - 4)] = 0.0f;   // row pos=512

    // ---- device barrier 1: counts + ord-init complete everywhere ----
    __threadfence();
    __syncthreads();
    if (tid == 0) {
        atomicAdd(&wsI[WS_ARR1], 1);
        while (atomicAdd(&wsI[WS_ARR1], 0) < GRID) {}
    }
    __syncthreads();

    // ---- phase 1: every block computes identical bases (wave 0, pair-padded scan) ----
    if (tid < 64) {
        unsigned pref[8];
        unsigned s = 0;
        #pragma unroll
        for (int i = 0; i < 8; ++i) {
            unsigned cc = (unsigned)wsI[WS_CNT + tid * 8 + i];
            cc = (cc + 1u) & ~1u;
            pref[i] = s;
            s += cc;
        }
        unsigned sc = s;
        #pragma unroll
        for (int o = 1; o < 64; o <<= 1) {
            unsigned up = (unsigned)__shfl_up((int)sc, o, 64);
            if (tid >= o) sc += up;
        }
        unsigned lanebase = sc - s;
        #pragma unroll
        for (int i = 0; i < 8; ++i) smi[SBASE_OFF + tid * 8 + i] = (int)(lanebase + pref[i]);
        if (tid == 63) smi[STOT_OFF] = (int)sc;
    }
    __syncthreads();

    // ---- phase 2: scatter into pair-aligned regions ----
    if (g < NK) {
        int slot = smi[SBASE_OFF + mykey] + atomicAdd(&wsI[WS_OFF + mykey], 1);
        wsI[WS_ORD + slot] = g;
    }

    // ---- device barrier 2: ord fully written ----
    __threadfence();
    __syncthreads();
    if (tid == 0) {
        atomicAdd(&wsI[WS_ARR2], 1);
        while (atomicAdd(&wsI[WS_ARR2], 0) < GRID) {}
    }
    __syncthreads();

    // ---- phase 3: pair main loop ----
    const int npairs = smi[STOT_OFF] >> 1;
    const float4* rows = (const float4*)sm;
    unsigned int* red = (unsigned int*)(sm + RED_OFF);
    const int tb = tid * 10;                 // 40B stride, 8B aligned
    const int wbase = (tid & ~63) * 10;
    const int sub = lane & 7;
    const int dv = lane >> 3;                // 0..3 = max half2s, 4..7 = cnt half2s
    const bool ismax = dv < 4;
    const half2v ninf2 = {(_Float16)(-INFINITY), (_Float16)(-INFINITY)};
    const half2v zz    = {(_Float16)0.f, (_Float16)0.f};

    for (int p = blockIdx.x * 4 + wave; p < npairs; p += GRID * 4) {
        int kq[2];
        #pragma unroll
        for (int q = 0; q < 2; ++q)
            kq[q] = __builtin_amdgcn_readfirstlane(wsI[WS_ORD + 2 * p + q]);

        half2v wh[2][KSMAX];
        half2v bb[2];
        int pq[2], lkq[2];
        float w7 = 0.f, w8 = 0.f, w9 = 0.f, w10 = 0.f;
        int dl = 1;
        #pragma unroll
        for (int q = 0; q < 2; ++q) {
            int k = kq[q];
            if (k >= 0) {
                const float* wr = W + (size_t)k * KSMAX;
                #pragma unroll
                for (int j = 0; j < KSMAX; ++j) {
                    _Float16 wf = (_Float16)wr[j];
                    wh[q][j] = (half2v){wf, wf};
                }
                _Float16 bf = (_Float16)bias[k];
                bb[q] = (half2v){bf, bf};
                lkq[q] = lo[k];
                if (q == 0) { w7 = wr[7]; w8 = wr[8]; w9 = wr[9]; w10 = wr[10]; dl = dil[k]; }
            } else {
                #pragma unroll
                for (int j = 0; j < KSMAX; ++j) wh[q][j] = (half2v){(_Float16)0.f, (_Float16)0.f};
                bb[q] = (half2v){(_Float16)0.f, (_Float16)0.f};
                lkq[q] = 0;
            }
        }
        const int ksi = (w7 == 0.f && w8 == 0.f && w9 == 0.f && w10 == 0.f) ? 0
                      : ((w9 == 0.f && w10 == 0.f) ? 1 : 2);
        const int ks = 7 + 2 * ksi;          // pair-uniform (key includes ksi)
        int r_lo = 0, r_hi = 0;
        #pragma unroll
        for (int q = 0; q < 2; ++q) {
            if (kq[q] >= 0) {
                pq[q] = (lkq[q] - LSEQ + dl * (ks - 1)) >> 1;   // lo = 512+2p-dl(ks-1)
                r_lo = min(r_lo, -pq[q]);
                r_hi = max(r_hi, lkq[q] - pq[q]);
            } else {
                pq[q] = 0;
            }
        }

        half2v m[2][4], c[2][4];
        #pragma unroll
        for (int q = 0; q < 2; ++q) {
            #pragma unroll
            for (int i = 0; i < 4; ++i) { m[q][i] = ninf2; c[q][i] = zz; }
        }

        if (ksi == 0)      run_pair<7 >(rows, wh, bb, pq, lkq, dl, r_lo, r_hi, lane, m, c);
        else if (ksi == 1) run_pair<9 >(rows, wh, bb, pq, lkq, dl, r_lo, r_hi, lane, m, c);
        else               run_pair<11>(rows, wh, bb, pq, lkq, dl, r_lo, r_hi, lane, m, c);

        // ---- wave-internal epilogue (no barriers: same-wave DS ordering) ----
        #pragma unroll
        for (int q = 0; q < 2; ++q) {
            if (kq[q] < 0) continue;         // wave-uniform
            H2U u0, u1, u2, u3;
            uint2 p01, p23;
            u0.h = m[q][0]; u1.h = m[q][1]; u2.h = m[q][2]; u3.h = m[q][3];
            p01.x = u0.u; p01.y = u1.u; p23.x = u2.u; p23.y = u3.u;
            *(uint2*)(red + tb + 0) = p01;
            *(uint2*)(red + tb + 2) = p23;
            u0.h = c[q][0]; u1.h = c[q][1]; u2.h = c[q][2]; u3.h = c[q][3];
            p01.x = u0.u; p01.y = u1.u; p23.x = u2.u; p23.y = u3.u;
            *(uint2*)(red + tb + 4) = p01;
            *(uint2*)(red + tb + 6) = p23;

            half2v r2 = ismax ? ninf2 : zz;
            #pragma unroll
            for (int i = 0; i < 8; ++i) {
                H2U t;
                t.u = red[wbase + (sub + 8 * i) * 10 + dv];
                r2 = ismax ? __builtin_elementwise_max(r2, t.h) : (r2 + t.h);
            }
            #pragma unroll
            for (int s = 1; s < 8; s <<= 1) {
                H2U me, ot;
                me.h = r2;
                ot.u = (unsigned int)__shfl_xor((int)me.u, s, 64);
                r2 = ismax ? __builtin_elementwise_max(r2, ot.h) : (r2 + ot.h);
            }
            if (sub == 0) {
                int kk = kq[q];
                if (ismax) {
                    int b = 2 * dv;
                    out[(size_t)b       * (2 * NK) + 2 * kk] = (float)r2.x;
                    out[(size_t)(b + 1) * (2 * NK) + 2 * kk] = (float)r2.y;
                } else {
                    int b = 2 * (dv - 4);
                    float inv = 1.0f / (float)lkq[q];
                    out[(size_t)b       * (2 * NK) + 2 * kk + 1] = (float)r2.x * inv;
                    out[(size_t)(b + 1) * (2 * NK) + 2 * kk + 1] = (float)r2.y * inv;
                }
            }
        }
    }
}

extern "C" void kernel_launch(void* const* d_in, const int* in_sizes, int n_in,
                              void* d_out, int out_size, void* d_ws, size_t ws_size,
                              hipStream_t stream) {
    const float* x    = (const float*)d_in[0];
    const float* W    = (const float*)d_in[1];
    const float* bias = (const float*)d_in[2];
    const int*   dil  = (const int*)d_in[4];
    const int*   lo   = (const int*)d_in[5];
    float* out = (float*)d_out;
    int* wsI = (int*)d_ws;

    hipMemsetAsync(wsI, 0, WS_ZERO_BYTES, stream);   // arrive1/2 + cnt + off
    rocket_kernel<<<GRID, 256, 0, stream>>>(x, W, bias, dil, lo, wsI, out);
}

// Round 11
// 112.473 us; speedup vs baseline: 2.6940x; 2.6940x over previous
//
#include <hip/hip_runtime.h>
#include <math.h>

#define NK        10000
#define LSEQ      512
#define KSMAX     11
#define NKEYS     512               // key = (((dl-1)*3+ksi)<<1)|pd  (max 505)
#define TOT_SLOT  11536             // 721 blocks * 16 quad-aligned slots >= NK + 3*NKEYS
#define GRID_MAIN 721
#define GRID_PREP 46                // 46*256 = 11776 >= TOT_SLOT

// workspace int offsets
#define WS_CNT    0                 // 512 counts (memset to 0)
#define WS_KEY    512               // NK keys
#define WS_REC    10512             // NK records of 16 dwords (16B aligned)
#define WS_ORD    170512            // TOT_SLOT slots

// LDS dword offsets (main)
#define ROWS_DW   (514 * 4)         // f16x8 rows pos=-1..512
#define RED_OFF   ROWS_DW
#define SM_DW     (ROWS_DW + 256 * 10)   // 18464 B

typedef _Float16 half2v __attribute__((ext_vector_type(2)));
union H2U { half2v h; unsigned int u; };

// ---- pass 1: classify, count, build per-k records (wh/bias/dl/lk/pad/ksi), init ord ----
__global__ __launch_bounds__(256) void prep_kernel(
    const float* __restrict__ W, const float* __restrict__ bias,
    const int* __restrict__ dil, const int* __restrict__ lo,
    int* __restrict__ wsI) {
    const int g = blockIdx.x * 256 + threadIdx.x;
    if (g < TOT_SLOT) wsI[WS_ORD + g] = -1;
    if (g >= NK) return;
    const float* wr = W + (size_t)g * KSMAX;
    float w7 = wr[7], w8 = wr[8], w9 = wr[9], w10 = wr[10];
    int ksi = (w7 == 0.f && w8 == 0.f && w9 == 0.f && w10 == 0.f) ? 0
            : ((w9 == 0.f && w10 == 0.f) ? 1 : 2);
    int d  = dil[g];
    int lk = lo[g];
    int pad = (lk - LSEQ + d * (6 + 2 * ksi)) >> 1;   // exact: lo = 512+2p-d(ks-1)
    int key = (((d - 1) * 3 + ksi) << 1) | (pad > 0);
    wsI[WS_KEY + g] = key;
    atomicAdd(&wsI[WS_CNT + key], 1);
    int* rec = wsI + WS_REC + (size_t)g * 16;
    #pragma unroll
    for (int j = 0; j < KSMAX; ++j) {
        _Float16 wf = (_Float16)wr[j];
        H2U u; u.h = (half2v){wf, wf};
        rec[j] = (int)u.u;
    }
    _Float16 bf = (_Float16)bias[g];
    H2U ub; ub.h = (half2v){bf, bf};
    rec[11] = (int)ub.u;
    rec[12] = d;
    rec[13] = lk;
    rec[14] = pad;
    rec[15] = ksi;
}

// ---- pass 2: quad-padded scan of counts + scatter k's into ord (single block) ----
__global__ __launch_bounds__(1024) void scatter_kernel(int* __restrict__ wsI) {
    __shared__ int sbase[NKEYS];
    __shared__ int soff[NKEYS];
    const int tid = threadIdx.x;
    if (tid < NKEYS) soff[tid] = 0;
    if (tid < 64) {
        unsigned pref[8];
        unsigned s = 0;
        #pragma unroll
        for (int i = 0; i < 8; ++i) {
            unsigned cc = (unsigned)wsI[WS_CNT + tid * 8 + i];
            cc = (cc + 3u) & ~3u;                      // quad-pad each group
            pref[i] = s;
            s += cc;
        }
        unsigned sc = s;
        #pragma unroll
        for (int o = 1; o < 64; o <<= 1) {
            unsigned up = (unsigned)__shfl_up((int)sc, o, 64);
            if (tid >= o) sc += up;
        }
        unsigned lanebase = sc - s;
        #pragma unroll
        for (int i = 0; i < 8; ++i) sbase[tid * 8 + i] = (int)(lanebase + pref[i]);
    }
    __syncthreads();
    for (int i = tid; i < NK; i += 1024) {
        int kk = wsI[WS_KEY + i];
        int slot = sbase[kk] + atomicAdd(&soff[kk], 1);
        wsI[WS_ORD + slot] = i;
    }
}

// ---- quad main loop: ONE ds_read_b128 per tap serves 4 kernels; weights via s_load ----
template <int KS>
__device__ __forceinline__ void run_quad(const float4* __restrict__ rows,
                                         const int* const (&rec)[4],
                                         const int (&pq)[4], const int (&lkq)[4],
                                         int dl, int r_lo, int r_hi, int lane,
                                         half2v (&m)[4][4], half2v (&c)[4][4]) {
    const half2v one2  = {(_Float16)1.0f, (_Float16)1.0f};
    const half2v zero2 = {(_Float16)0.0f, (_Float16)0.0f};
    const half2v big2  = {(_Float16)16384.0f, (_Float16)16384.0f};
    const half2v ninf2 = {(_Float16)(-INFINITY), (_Float16)(-INFINITY)};
    for (int r0 = r_lo; r0 < r_hi; r0 += 64) {
        const int r = r0 + lane;
        half2v a[4][4];
        #pragma unroll
        for (int q = 0; q < 4; ++q) {
            H2U b; b.u = (unsigned)rec[q][11];
            #pragma unroll
            for (int i = 0; i < 4; ++i) a[q][i] = b.h;
        }
        int pos = r;
        #pragma unroll
        for (int j = 0; j < KS; ++j) {
            int pc = min(max(pos, -1), LSEQ);          // v_med3_i32; rows -1/512 are zeros
            float4 rr = rows[pc + 1];
            half2v v0 = ((half2v*)&rr)[0];
            half2v v1 = ((half2v*)&rr)[1];
            half2v v2 = ((half2v*)&rr)[2];
            half2v v3 = ((half2v*)&rr)[3];
            #pragma unroll
            for (int q = 0; q < 4; ++q) {
                H2U w; w.u = (unsigned)rec[q][j];      // uniform -> SGPR operand
                half2v wj = w.h;
                a[q][0] += wj * v0;                    // v_pk_fma_f16
                a[q][1] += wj * v1;
                a[q][2] += wj * v2;
                a[q][3] += wj * v3;
            }
            pos += dl;
        }
        #pragma unroll
        for (int q = 0; q < 4; ++q) {
            unsigned t = (unsigned)(r + pq[q]);
            bool valid = t < (unsigned)lkq[q];
            #pragma unroll
            for (int i = 0; i < 4; ++i) {
                half2v av = valid ? a[q][i] : ninf2;   // -inf: neutral for max, step()->0
                m[q][i] = __builtin_elementwise_max(m[q][i], av);
                c[q][i] += __builtin_elementwise_min(
                               __builtin_elementwise_max(av * big2, zero2), one2);
            }
        }
    }
}

__global__ __launch_bounds__(256) void rocket_kernel(
    const float* __restrict__ x, const int* __restrict__ wsI,
    float* __restrict__ out) {
    __shared__ __align__(16) float sm[SM_DW];
    const int tid = threadIdx.x;
    if (wsI[WS_ORD + blockIdx.x * 16] < 0) return;   // dense slots -> whole block dummy

    // ---- stage x -> LDS as f16, batch-major 16B rows; one row per thread ----
    #pragma unroll
    for (int i = 0; i < 2; ++i) {
        int p = tid + i * 256;
        half2v h0 = {(_Float16)x[0 * LSEQ + p], (_Float16)x[1 * LSEQ + p]};
        half2v h1 = {(_Float16)x[2 * LSEQ + p], (_Float16)x[3 * LSEQ + p]};
        half2v h2 = {(_Float16)x[4 * LSEQ + p], (_Float16)x[5 * LSEQ + p]};
        half2v h3 = {(_Float16)x[6 * LSEQ + p], (_Float16)x[7 * LSEQ + p]};
        float4 v;
        ((half2v*)&v)[0] = h0;
        ((half2v*)&v)[1] = h1;
        ((half2v*)&v)[2] = h2;
        ((half2v*)&v)[3] = h3;
        *(float4*)(sm + (size_t)(p + 1) * 4) = v;
    }
    if (tid < 4)           sm[tid] = 0.0f;                   // row pos=-1
    else if (tid < 8)      sm[513 * 4 + (tid - 4)] = 0.0f;   // row pos=512

    const int wave = tid >> 6;
    const int lane = tid & 63;

    // ---- quad setup (wave-uniform; records read via scalar loads) ----
    int kq[4];
    #pragma unroll
    for (int q = 0; q < 4; ++q)
        kq[q] = __builtin_amdgcn_readfirstlane(wsI[WS_ORD + blockIdx.x * 16 + wave * 4 + q]);

    const int* rec[4];
    int pq[4], lkq[4];
    int k0 = (kq[0] >= 0) ? kq[0] : 0;
    #pragma unroll
    for (int q = 0; q < 4; ++q) {
        int k = (kq[q] >= 0) ? kq[q] : k0;
        rec[q] = wsI + WS_REC + (size_t)k * 16;
        if (kq[q] >= 0) { lkq[q] = rec[q][13]; pq[q] = rec[q][14]; }
        else            { lkq[q] = 0;          pq[q] = 0; }
    }
    const int dl  = (kq[0] >= 0) ? rec[0][12] : 1;
    const int ksi = (kq[0] >= 0) ? rec[0][15] : 0;   // group-uniform (key includes ksi)
    int r_lo = 0, r_hi = 0;
    #pragma unroll
    for (int q = 0; q < 4; ++q) {
        if (kq[q] >= 0) {
            r_lo = min(r_lo, -pq[q]);
            r_hi = max(r_hi, lkq[q] - pq[q]);
        }
    }

    __syncthreads();   // rows visible to all waves

    const half2v ninf2 = {(_Float16)(-INFINITY), (_Float16)(-INFINITY)};
    const half2v zz    = {(_Float16)0.f, (_Float16)0.f};
    half2v m[4][4], c[4][4];
    #pragma unroll
    for (int q = 0; q < 4; ++q) {
        #pragma unroll
        for (int i = 0; i < 4; ++i) { m[q][i] = ninf2; c[q][i] = zz; }
    }

    const float4* rows = (const float4*)sm;
    if (ksi == 0)      run_quad<7 >(rows, rec, pq, lkq, dl, r_lo, r_hi, lane, m, c);
    else if (ksi == 1) run_quad<9 >(rows, rec, pq, lkq, dl, r_lo, r_hi, lane, m, c);
    else               run_quad<11>(rows, rec, pq, lkq, dl, r_lo, r_hi, lane, m, c);

    // ---- wave-internal epilogue per quad entry (no barriers: same-wave DS ordering) ----
    unsigned int* red = (unsigned int*)(sm + RED_OFF);
    const int tb = tid * 10;                 // 40B stride, 8B aligned
    const int wbase = (tid & ~63) * 10;
    const int sub = lane & 7;
    const int dv = lane >> 3;                // 0..3 = max half2s, 4..7 = cnt half2s
    const bool ismax = dv < 4;
    #pragma unroll
    for (int q = 0; q < 4; ++q) {
        if (kq[q] < 0) continue;             // wave-uniform
        H2U u0, u1, u2, u3;
        uint2 p01, p23;
        u0.h = m[q][0]; u1.h = m[q][1]; u2.h = m[q][2]; u3.h = m[q][3];
        p01.x = u0.u; p01.y = u1.u; p23.x = u2.u; p23.y = u3.u;
        *(uint2*)(red + tb + 0) = p01;
        *(uint2*)(red + tb + 2) = p23;
        u0.h = c[q][0]; u1.h = c[q][1]; u2.h = c[q][2]; u3.h = c[q][3];
        p01.x = u0.u; p01.y = u1.u; p23.x = u2.u; p23.y = u3.u;
        *(uint2*)(red + tb + 4) = p01;
        *(uint2*)(red + tb + 6) = p23;

        half2v r2 = ismax ? ninf2 : zz;
        #pragma unroll
        for (int i = 0; i < 8; ++i) {
            H2U t;
            t.u = red[wbase + (sub + 8 * i) * 10 + dv];
            r2 = ismax ? __builtin_elementwise_max(r2, t.h) : (r2 + t.h);
        }
        #pragma unroll
        for (int s = 1; s < 8; s <<= 1) {
            H2U me, ot;
            me.h = r2;
            ot.u = (unsigned int)__shfl_xor((int)me.u, s, 64);
            r2 = ismax ? __builtin_elementwise_max(r2, ot.h) : (r2 + ot.h);
        }
        if (sub == 0) {
            int kk = kq[q];
            if (ismax) {
                int b = 2 * dv;
                out[(size_t)b       * (2 * NK) + 2 * kk] = (float)r2.x;
                out[(size_t)(b + 1) * (2 * NK) + 2 * kk] = (float)r2.y;
            } else {
                int b = 2 * (dv - 4);
                float inv = 1.0f / (float)lkq[q];
                out[(size_t)b       * (2 * NK) + 2 * kk + 1] = (float)r2.x * inv;
                out[(size_t)(b + 1) * (2 * NK) + 2 * kk + 1] = (float)r2.y * inv;
            }
        }
    }
}

extern "C" void kernel_launch(void* const* d_in, const int* in_sizes, int n_in,
                              void* d_out, int out_size, void* d_ws, size_t ws_size,
                              hipStream_t stream) {
    const float* x    = (const float*)d_in[0];
    const float* W    = (const float*)d_in[1];
    const float* bias = (const float*)d_in[2];
    const int*   dil  = (const int*)d_in[4];
    const int*   lo   = (const int*)d_in[5];
    float* out = (float*)d_out;
    int* wsI = (int*)d_ws;

    hipMemsetAsync(wsI + WS_CNT, 0, NKEYS * sizeof(int), stream);
    prep_kernel<<<GRID_PREP, 256, 0, stream>>>(W, bias, dil, lo, wsI);
    scatter_kernel<<<1, 1024, 0, stream>>>(wsI);
    rocket_kernel<<<GRID_MAIN, 256, 0, stream>>>(x, wsI, out);
}